// Round 4
// baseline (995.829 us; speedup 1.0000x reference)
//
#include <hip/hip_runtime.h>
#include <math.h>

#define DDIM 16
#define NSTEPS 64
#define BATCH_N 2097152L   // fixed problem size: 2^21 rows (do NOT trust in_sizes units)

typedef _Float16 half4   __attribute__((ext_vector_type(4)));
typedef __fp16   fp16x2  __attribute__((ext_vector_type(2)));  // cvt_pkrtz return type
typedef float    floatx4 __attribute__((ext_vector_type(4)));

// Packed per-lane MFMA A-operand fragments for W^T and (V^T * 0.5/N), f16.
// 64 steps * 64 lanes * 8 B = 32 KB each. Module-scope device memory.
// The 0.5 from gelu(x)=0.5*x*(1+tanh(a)) and the 1/N residual scale are BOTH
// folded into V, so the kernel feeds g = x*(1+tanh(a)) straight to the MFMA.
__device__ half4 g_pw[NSTEPS * 64];
__device__ half4 g_pv[NSTEPS * 64];

__global__ __launch_bounds__(256) void pack_wv(const float* __restrict__ W,
                                               const float* __restrict__ V)
{
    int t = blockIdx.x * 256 + threadIdx.x;   // 0..4095 = 64 steps * 64 lanes
    int L = t & 63;
    int s = t >> 6;
    int q = L >> 4, r = L & 15;
    const float vscale = 0.5f / (float)NSTEPS;   // gelu 0.5 * residual 1/N
    const float* Ws = W + s * DDIM * DDIM;
    const float* Vs = V + s * DDIM * DDIM;
    half4 w, v;
    #pragma unroll
    for (int j = 0; j < 4; ++j) {
        w[j] = (_Float16)Ws[(4 * q + j) * DDIM + r];
        v[j] = (_Float16)(Vs[(4 * q + j) * DDIM + r] * vscale);
    }
    g_pw[t] = w;
    g_pv[t] = v;
}

// ---------------------------------------------------------------------------
// Main kernel: each wave owns 4 row-tiles (64 rows). State h kept in fp32 in
// the MFMA C/D layout. Chain: u^T = W^T @ h^T ; h^T += V'^T @ (u*(1+tanh))^T.
//
// R3 change: GELU's exp2+rcp (32 trans ops/step @ ~16cy each = 66% of issue
// budget at VALUBusy=96%) replaced by Padé[5/4] tanh:
//     tanh(a) ~= a*(a^4+105a^2+945) / (15a^4+420a^2+945), clamped to [-1,1].
// Exact-integer coefficients; max err ~5e-4 (below f16 quantization of g).
// The single divide per element is 4-BATCHED per tile: one v_rcp of the
// product of 4 denominators + 8 muls recovers all four reciprocals.
// den >= 945 always -> no div0/NaN; 4-product <= ~1e24 -> no overflow.
// Trans ops per step: 32 -> 4.
// ---------------------------------------------------------------------------
__global__ __launch_bounds__(256, 6) void resnet_mfma_kernel(
    const float* __restrict__ x,
    float* __restrict__ out)
{
    const int tid  = threadIdx.x;
    const int lane = tid & 63;
    const int wave = tid >> 6;
    const int q = lane >> 4, r = lane & 15;

    const long rowbase = (long)blockIdx.x * 256 + (long)wave * 64;

    // Load state: lane reads float4 at (row, 4q) for each of its 4 tiles.
    floatx4 h[4];
    #pragma unroll
    for (int t = 0; t < 4; ++t) {
        const float4* p = reinterpret_cast<const float4*>(
            x + (rowbase + t * 16 + r) * DDIM + 4 * q);
        float4 v = *p;
        h[t][0] = v.x; h[t][1] = v.y; h[t][2] = v.z; h[t][3] = v.w;
    }

    // a = 0.7978845608 * x * (1 + 0.044715 x^2) = x * fma(C1, x^2, C0)
    const float C0 = 0.79788456f;
    const float C1 = 0.035677408f;   // 0.044715 * C0

    // Software-prefetch the W/V fragments one step ahead (L1/L2-hot, 64KB total).
    half4 wf = g_pw[lane];
    half4 vf = g_pv[lane];

    for (int s = 0; s < NSTEPS; ++s) {
        int sn = (s < NSTEPS - 1) ? s + 1 : s;
        half4 wfn = g_pw[sn * 64 + lane];
        half4 vfn = g_pv[sn * 64 + lane];

        // Phase 1: h (fp32, C/D layout) -> f16 B-operand, all tiles.
        union { fp16x2 h2[2]; half4 h4; } hb[4];
        #pragma unroll
        for (int t = 0; t < 4; ++t) {
            hb[t].h2[0] = __builtin_amdgcn_cvt_pkrtz(h[t][0], h[t][1]);
            hb[t].h2[1] = __builtin_amdgcn_cvt_pkrtz(h[t][2], h[t][3]);
        }

        // Phase 2: u = W^T @ h^T, all tiles (4 independent MFMAs).
        floatx4 u[4];
        #pragma unroll
        for (int t = 0; t < 4; ++t) {
            floatx4 zero = {0.f, 0.f, 0.f, 0.f};
            u[t] = __builtin_amdgcn_mfma_f32_16x16x16f16(wf, hb[t].h4, zero, 0, 0, 0);
        }

        // Phase 3: g = u * (1 + tanh_pade(a(u))) -> f16 (0.5 folded into V).
        union { fp16x2 h2[2]; half4 h4; } gb[4];
        #pragma unroll
        for (int t = 0; t < 4; ++t) {
            float an[4], np[4], dn[4];
            #pragma unroll
            for (int j = 0; j < 4; ++j) {
                float xv = u[t][j];
                float x2 = xv * xv;
                float t1 = fmaf(C1, x2, C0);
                float a  = xv * t1;
                float a2 = a * a;
                float s1 = a2 + 105.0f;
                np[j] = fmaf(s1, a2, 945.0f);                       // a^4+105a^2+945
                dn[j] = fmaf(fmaf(15.0f, a2, 420.0f), a2, 945.0f);  // 15a^4+420a^2+945
                an[j] = a;
            }
            // 4-batched reciprocal: one trans op for four divides.
            float p01 = dn[0] * dn[1];
            float p23 = dn[2] * dn[3];
            float R   = __builtin_amdgcn_rcpf(p01 * p23);
            float r01 = R * p23, r23 = R * p01;
            float rr0 = r01 * dn[1], rr1 = r01 * dn[0];
            float rr2 = r23 * dn[3], rr3 = r23 * dn[2];
            float rr[4] = { rr0, rr1, rr2, rr3 };
            float g[4];
            #pragma unroll
            for (int j = 0; j < 4; ++j) {
                float th = (an[j] * np[j]) * rr[j];
                th = __builtin_amdgcn_fmed3f(th, -1.0f, 1.0f);      // clamp tanh
                g[j] = fmaf(u[t][j], th, u[t][j]);                  // u*(1+tanh)
            }
            gb[t].h2[0] = __builtin_amdgcn_cvt_pkrtz(g[0], g[1]);
            gb[t].h2[1] = __builtin_amdgcn_cvt_pkrtz(g[2], g[3]);
        }

        // Phase 4: h += g @ (V*0.5/N), all tiles (residual in MFMA C operand).
        #pragma unroll
        for (int t = 0; t < 4; ++t) {
            h[t] = __builtin_amdgcn_mfma_f32_16x16x16f16(vf, gb[t].h4, h[t], 0, 0, 0);
        }

        wf = wfn; vf = vfn;
    }

    #pragma unroll
    for (int t = 0; t < 4; ++t) {
        float4 v = make_float4(h[t][0], h[t][1], h[t][2], h[t][3]);
        *reinterpret_cast<float4*>(out + (rowbase + t * 16 + r) * DDIM + 4 * q) = v;
    }
}

extern "C" void kernel_launch(void* const* d_in, const int* in_sizes, int n_in,
                              void* d_out, int out_size, void* d_ws, size_t ws_size,
                              hipStream_t stream) {
    (void)in_sizes; (void)n_in; (void)out_size; (void)d_ws; (void)ws_size;

    const float* x = (const float*)d_in[0];   // [2^21, 16] fp32
    const float* W = (const float*)d_in[1];   // [64, 16, 16] fp32
    const float* V = (const float*)d_in[2];   // [64, 16, 16] fp32
    float* out = (float*)d_out;

    pack_wv<<<16, 256, 0, stream>>>(W, V);

    // Problem size fixed by spec; grid hard-coded.
    resnet_mfma_kernel<<<(int)(BATCH_N / 256), 256, 0, stream>>>(x, out);
}

// Round 7
// 762.260 us; speedup vs baseline: 1.3064x; 1.3064x over previous
//
#include <hip/hip_runtime.h>
#include <math.h>

#define DDIM 16
#define NSTEPS 64
#define BATCH_N 2097152L   // fixed problem size: 2^21 rows (do NOT trust in_sizes units)

typedef _Float16 half4   __attribute__((ext_vector_type(4)));
typedef __fp16   fp16x2  __attribute__((ext_vector_type(2)));  // cvt_pkrtz return type
typedef float    floatx4 __attribute__((ext_vector_type(4)));

// Packed per-lane MFMA A-operand fragments for W^T and (V^T * 1/N), f16.
// Scale is 1/N (not 0.5/N): the LDS table returns the FULL gelu factor
// S(z) = 2^z/(1+2^z) = 0.5*(1+tanh(a)), i.e. gelu(u) = u*S(z).
__device__ half4 g_pw[NSTEPS * 64];
__device__ half4 g_pv[NSTEPS * 64];

__global__ __launch_bounds__(256) void pack_wv(const float* __restrict__ W,
                                               const float* __restrict__ V)
{
    int t = blockIdx.x * 256 + threadIdx.x;   // 0..4095 = 64 steps * 64 lanes
    int L = t & 63;
    int s = t >> 6;
    int q = L >> 4, r = L & 15;
    const float vscale = 1.0f / (float)NSTEPS;
    const float* Ws = W + s * DDIM * DDIM;
    const float* Vs = V + s * DDIM * DDIM;
    half4 w, v;
    #pragma unroll
    for (int j = 0; j < 4; ++j) {
        w[j] = (_Float16)Ws[(4 * q + j) * DDIM + r];
        v[j] = (_Float16)(Vs[(4 * q + j) * DDIM + r] * vscale);
    }
    g_pw[t] = w;
    g_pv[t] = v;
}

// ---------------------------------------------------------------------------
// R7 = R6 (GELU via LDS lookup table) with a provably in-bounds table read.
// Rationale (R3 cycle model): 32 v_exp/v_rcp per step @ ~16cy = ~66% of VALU
// busy; LDS pipe idle. Table: S(z) = 1/(1+2^-z), z in [-16,16], 1024 linear-
// interp intervals (err ~6e-6 << f16 quantization of g).
// gelu(u) = u*S(z), z = K*u*(1+c1*u^2); coord map folded into constants:
//   tc = fma(u, fma(32*K*c1, u^2, 32*K), 512), clamped to [0, 1023.995].
// R6 crashed with a device fault; only new fault-capable instr was this
// indexed ds_read. Hardened: idx masked with &1023 (1 v_and_b32/elem) so the
// read is in-bounds for EVERY possible bit pattern; fr computed as
// tc - (float)idx (no fract builtin). Saturation unchanged for finite u.
// ---------------------------------------------------------------------------
__global__ __launch_bounds__(256, 6) void resnet_mfma_kernel(
    const float* __restrict__ x,
    float* __restrict__ out)
{
    __shared__ float2 tab[1024];   // 8 KB: {S(z0), S(z0+h)-S(z0)} per interval

    const int tid  = threadIdx.x;
    for (int k = tid; k < 1024; k += 256) {
        float z0 = -16.0f + (float)k * (1.0f / 32.0f);
        float z1 = z0 + (1.0f / 32.0f);
        float s0 = 1.0f / (1.0f + exp2f(-z0));
        float s1 = 1.0f / (1.0f + exp2f(-z1));
        tab[k] = make_float2(s0, s1 - s0);
    }

    const int lane = tid & 63;
    const int wave = tid >> 6;
    const int q = lane >> 4, r = lane & 15;

    const long rowbase = (long)blockIdx.x * 256 + (long)wave * 64;

    floatx4 h[4];
    #pragma unroll
    for (int t = 0; t < 4; ++t) {
        const float4* p = reinterpret_cast<const float4*>(
            x + (rowbase + t * 16 + r) * DDIM + 4 * q);
        float4 v = *p;
        h[t][0] = v.x; h[t][1] = v.y; h[t][2] = v.z; h[t][3] = v.w;
    }

    // tc(u) = 32*z + 512, z = u*(K + K*c1*u^2), K = 2.3022082, K*c1 = 0.1029434
    const float K32   = 73.670662f;    // 32 * K
    const float Kc132 = 3.2941887f;    // 32 * K * c1

    half4 wf = g_pw[lane];
    half4 vf = g_pv[lane];

    __syncthreads();   // table ready

    for (int s = 0; s < NSTEPS; ++s) {
        int sn = (s < NSTEPS - 1) ? s + 1 : s;
        half4 wfn = g_pw[sn * 64 + lane];
        half4 vfn = g_pv[sn * 64 + lane];

        // Phase 1: h (fp32, C/D layout) -> f16 B-operand, all tiles.
        union { fp16x2 h2[2]; half4 h4; } hb[4];
        #pragma unroll
        for (int t = 0; t < 4; ++t) {
            hb[t].h2[0] = __builtin_amdgcn_cvt_pkrtz(h[t][0], h[t][1]);
            hb[t].h2[1] = __builtin_amdgcn_cvt_pkrtz(h[t][2], h[t][3]);
        }

        // Phase 2: u = W^T @ h^T, all tiles.
        floatx4 u[4];
        #pragma unroll
        for (int t = 0; t < 4; ++t) {
            floatx4 zero = {0.f, 0.f, 0.f, 0.f};
            u[t] = __builtin_amdgcn_mfma_f32_16x16x16f16(wf, hb[t].h4, zero, 0, 0, 0);
        }

        // Phase 3: g = u * S_table(z(u)) -> f16.
        union { fp16x2 h2[2]; half4 h4; } gb[4];
        #pragma unroll
        for (int t = 0; t < 4; ++t) {
            float g[4];
            #pragma unroll
            for (int j = 0; j < 4; ++j) {
                float xv = u[t][j];
                float tc = fmaf(xv, fmaf(Kc132, xv * xv, K32), 512.0f);
                tc = __builtin_amdgcn_fmed3f(tc, 0.0f, 1023.995f);
                int   idx = ((int)tc) & 1023;        // provably in-bounds
                float fr  = tc - (float)idx;         // frac part (idx<=tc<idx+1)
                float2 ab = tab[idx];
                g[j] = xv * fmaf(fr, ab.y, ab.x);
            }
            gb[t].h2[0] = __builtin_amdgcn_cvt_pkrtz(g[0], g[1]);
            gb[t].h2[1] = __builtin_amdgcn_cvt_pkrtz(g[2], g[3]);
        }

        // Phase 4: h += g @ (V/N), all tiles (residual in MFMA C operand).
        #pragma unroll
        for (int t = 0; t < 4; ++t) {
            h[t] = __builtin_amdgcn_mfma_f32_16x16x16f16(vf, gb[t].h4, h[t], 0, 0, 0);
        }

        wf = wfn; vf = vfn;
    }

    #pragma unroll
    for (int t = 0; t < 4; ++t) {
        float4 v = make_float4(h[t][0], h[t][1], h[t][2], h[t][3]);
        *reinterpret_cast<float4*>(out + (rowbase + t * 16 + r) * DDIM + 4 * q) = v;
    }
}

extern "C" void kernel_launch(void* const* d_in, const int* in_sizes, int n_in,
                              void* d_out, int out_size, void* d_ws, size_t ws_size,
                              hipStream_t stream) {
    (void)in_sizes; (void)n_in; (void)out_size; (void)d_ws; (void)ws_size;

    const float* x = (const float*)d_in[0];   // [2^21, 16] fp32
    const float* W = (const float*)d_in[1];   // [64, 16, 16] fp32
    const float* V = (const float*)d_in[2];   // [64, 16, 16] fp32
    float* out = (float*)d_out;

    pack_wv<<<16, 256, 0, stream>>>(W, V);

    // Problem size fixed by spec; grid hard-coded.
    resnet_mfma_kernel<<<(int)(BATCH_N / 256), 256, 0, stream>>>(x, out);
}

// Round 8
// 553.215 us; speedup vs baseline: 1.8001x; 1.3779x over previous
//
#include <hip/hip_runtime.h>
#include <math.h>

#define DDIM 16
#define NSTEPS 64
#define BATCH_N 2097152L   // fixed problem size: 2^21 rows (do NOT trust in_sizes units)
#define TABN 8192          // GELU table entries, u in [-16,16], h = 1/256

typedef _Float16 half4   __attribute__((ext_vector_type(4)));
typedef __fp16   fp16x2  __attribute__((ext_vector_type(2)));  // cvt_pkrtz return type
typedef float    floatx4 __attribute__((ext_vector_type(4)));

// Packed per-lane MFMA A-operand fragments for W^T and (V^T * 1/N), f16,
// plus the exact-erf GELU lookup table G(u) in f16.
// Scale is 1/N: the table returns the FULL gelu value, g = G(u).
__device__ half4    g_pw[NSTEPS * 64];
__device__ half4    g_pv[NSTEPS * 64];
__device__ _Float16 g_tab[TABN];

__global__ __launch_bounds__(256) void pack_wv(const float* __restrict__ W,
                                               const float* __restrict__ V)
{
    int t = blockIdx.x * 256 + threadIdx.x;   // 0..4095 = 64 steps * 64 lanes
    int L = t & 63;
    int s = t >> 6;
    int q = L >> 4, r = L & 15;
    const float vscale = 1.0f / (float)NSTEPS;
    const float* Ws = W + s * DDIM * DDIM;
    const float* Vs = V + s * DDIM * DDIM;
    half4 w, v;
    #pragma unroll
    for (int j = 0; j < 4; ++j) {
        w[j] = (_Float16)Ws[(4 * q + j) * DDIM + r];
        v[j] = (_Float16)(Vs[(4 * q + j) * DDIM + r] * vscale);
    }
    g_pw[t] = w;
    g_pv[t] = v;

    // GELU table: entry k covers u in [(k-4096.5)/256, (k-4095.5)/256);
    // value = exact-erf GELU at the interval center u_k = (k-4096)/256.
    // f16 round-to-nearest storage (BETTER than the RTZ cvt it replaces).
    #pragma unroll
    for (int e = 0; e < 2; ++e) {
        int   k  = 2 * t + e;
        float u  = ((float)k - 4096.0f) * (1.0f / 256.0f);
        float gg = 0.5f * u * (1.0f + erff(u * 0.70710678f));
        g_tab[k] = (_Float16)gg;
    }
}

// ---------------------------------------------------------------------------
// R8: GELU = direct 1-D lookup of G(u) (exact erf), f16, nearest-neighbor.
// Lesson from R3/R4/R7: pipes are issue-additive; win = cut total ops.
// Per element: fma(u,256,4096.5) -> med3 clamp -> cvt_i32 -> &8191 ->
// ds_read_u16. 4 full-rate + one 2-byte LDS read (R7: ~10 + b64 w/ 1.5e8
// conflicts; R3: 5 + 2 trans). Table value IS the f16 g -> no g-side cvt.
// Accuracy: nearest err <= |G'|*h/2 ~ 2.2e-3, below f16 quantization of g;
// exact-erf table REMOVES the tanh-approx systematic error. |u|>16 is
// unreachable (u ~ N(0,~1)); med3+mask guarantee in-bounds for any bits.
// u16 gather spread (sigma ~256 entries) is near-uniform over 32 banks.
// ---------------------------------------------------------------------------
__global__ __launch_bounds__(256, 8) void resnet_mfma_kernel(
    const float* __restrict__ x,
    float* __restrict__ out)
{
    __shared__ _Float16 tab[TABN];   // 16 KB

    const int tid = threadIdx.x;

    // Block-copy table global -> LDS: 16384 B / (256 thr * 16 B) = 4 float4s.
    {
        const float4* src = reinterpret_cast<const float4*>(g_tab);
        float4*       dst = reinterpret_cast<float4*>(tab);
        #pragma unroll
        for (int k = 0; k < 4; ++k)
            dst[tid + 256 * k] = src[tid + 256 * k];
    }

    const int lane = tid & 63;
    const int wave = tid >> 6;
    const int q = lane >> 4, r = lane & 15;

    const long rowbase = (long)blockIdx.x * 256 + (long)wave * 64;

    floatx4 h[4];
    #pragma unroll
    for (int t = 0; t < 4; ++t) {
        const float4* p = reinterpret_cast<const float4*>(
            x + (rowbase + t * 16 + r) * DDIM + 4 * q);
        float4 v = *p;
        h[t][0] = v.x; h[t][1] = v.y; h[t][2] = v.z; h[t][3] = v.w;
    }

    half4 wf = g_pw[lane];
    half4 vf = g_pv[lane];

    __syncthreads();   // table ready

    for (int s = 0; s < NSTEPS; ++s) {
        int sn = (s < NSTEPS - 1) ? s + 1 : s;
        half4 wfn = g_pw[sn * 64 + lane];
        half4 vfn = g_pv[sn * 64 + lane];

        // Phase 1: h (fp32, C/D layout) -> f16 B-operand, all tiles.
        union { fp16x2 h2[2]; half4 h4; } hb[4];
        #pragma unroll
        for (int t = 0; t < 4; ++t) {
            hb[t].h2[0] = __builtin_amdgcn_cvt_pkrtz(h[t][0], h[t][1]);
            hb[t].h2[1] = __builtin_amdgcn_cvt_pkrtz(h[t][2], h[t][3]);
        }

        // Phase 2: u = W^T @ h^T, all tiles.
        floatx4 u[4];
        #pragma unroll
        for (int t = 0; t < 4; ++t) {
            floatx4 zero = {0.f, 0.f, 0.f, 0.f};
            u[t] = __builtin_amdgcn_mfma_f32_16x16x16f16(wf, hb[t].h4, zero, 0, 0, 0);
        }

        // Phase 3: g = G_table(u), f16 directly from LDS.
        half4 gb[4];
        #pragma unroll
        for (int t = 0; t < 4; ++t) {
            half4 g4;
            #pragma unroll
            for (int j = 0; j < 4; ++j) {
                float tc = fmaf(u[t][j], 256.0f, 4096.5f);   // +0.5 = round-nearest
                tc = __builtin_amdgcn_fmed3f(tc, 0.0f, 8191.0f);
                int idx = ((int)tc) & (TABN - 1);            // provably in-bounds
                g4[j] = tab[idx];
            }
            gb[t] = g4;
        }

        // Phase 4: h += g @ (V/N), all tiles (residual in MFMA C operand).
        #pragma unroll
        for (int t = 0; t < 4; ++t) {
            h[t] = __builtin_amdgcn_mfma_f32_16x16x16f16(vf, gb[t], h[t], 0, 0, 0);
        }

        wf = wfn; vf = vfn;
    }

    #pragma unroll
    for (int t = 0; t < 4; ++t) {
        float4 v = make_float4(h[t][0], h[t][1], h[t][2], h[t][3]);
        *reinterpret_cast<float4*>(out + (rowbase + t * 16 + r) * DDIM + 4 * q) = v;
    }
}

extern "C" void kernel_launch(void* const* d_in, const int* in_sizes, int n_in,
                              void* d_out, int out_size, void* d_ws, size_t ws_size,
                              hipStream_t stream) {
    (void)in_sizes; (void)n_in; (void)out_size; (void)d_ws; (void)ws_size;

    const float* x = (const float*)d_in[0];   // [2^21, 16] fp32
    const float* W = (const float*)d_in[1];   // [64, 16, 16] fp32
    const float* V = (const float*)d_in[2];   // [64, 16, 16] fp32
    float* out = (float*)d_out;

    pack_wv<<<16, 256, 0, stream>>>(W, V);

    // Problem size fixed by spec; grid hard-coded.
    resnet_mfma_kernel<<<(int)(BATCH_N / 256), 256, 0, stream>>>(x, out);
}